// Round 8
// baseline (260.779 us; speedup 1.0000x reference)
//
#include <hip/hip_runtime.h>
#include <math.h>

typedef unsigned short u16;
typedef unsigned int u32;
typedef __bf16 bfrag8 __attribute__((ext_vector_type(8)));
typedef float f32x4 __attribute__((ext_vector_type(4)));

#define B_ 2
#define T_ 2048
#define H_ 16
#define D_ 64
#define C_ 1024
#define NQKV_ 3072

#define MFMA_BF16(a, b, c) __builtin_amdgcn_mfma_f32_16x16x32_bf16((a), (b), (c), 0, 0, 0)

__device__ __forceinline__ u16 f2bf(float f) {
  u32 u = __builtin_bit_cast(u32, f);
  u += 0x7fffu + ((u >> 16) & 1u);  // RNE
  return (u16)(u >> 16);
}

// async global->LDS, 16B/lane; lds dest = wave-uniform base + lane*16
__device__ __forceinline__ void load_lds16(const u16* gp, u16* lp) {
  __builtin_amdgcn_global_load_lds(
      (const __attribute__((address_space(1))) u32*)(const void*)gp,
      (__attribute__((address_space(3))) u32*)(void*)lp, 16, 0, 0);
}

// -------- fused prep: convert x->bf16 | transpose wqkv | transpose wproj --------
__global__ __launch_bounds__(256) void prep_k(const float* __restrict__ x,
                                              const float* __restrict__ wqkv,
                                              const float* __restrict__ wproj,
                                              u16* __restrict__ xb,
                                              u16* __restrict__ wqkvT,
                                              u16* __restrict__ wprojT) {
  __shared__ u16 tile[64][65];
  int bi = blockIdx.x;
  if (bi < 2048) {  // convert x
    size_t i = ((size_t)bi * 256 + threadIdx.x) * 8;
    const float* s = x + i;
    float4 a = *(const float4*)s, b = *(const float4*)(s + 4);
    union { uint4 v; u16 h[8]; } t;
    t.h[0] = f2bf(a.x); t.h[1] = f2bf(a.y); t.h[2] = f2bf(a.z); t.h[3] = f2bf(a.w);
    t.h[4] = f2bf(b.x); t.h[5] = f2bf(b.y); t.h[6] = f2bf(b.z); t.h[7] = f2bf(b.w);
    *(uint4*)(xb + i) = t.v;
    return;
  }
  const float* src;
  u16* dst;
  int K, N, bx, by;
  if (bi < 2816) {  // wqkv [1024][3072] -> [3072][1024]
    int t = bi - 2048;
    src = wqkv; dst = wqkvT; K = C_; N = NQKV_;
    bx = (t % 48) * 64; by = (t / 48) * 64;
  } else {  // wproj [1024][1024] -> [1024][1024]
    int t = bi - 2816;
    src = wproj; dst = wprojT; K = C_; N = C_;
    bx = (t & 15) * 64; by = (t >> 4) * 64;
  }
  for (int idx = threadIdx.x; idx < 4096; idx += 256) {
    int r = idx >> 6, c = idx & 63;
    tile[r][c] = f2bf(src[(size_t)(by + r) * N + bx + c]);
  }
  __syncthreads();
  for (int idx = threadIdx.x; idx < 4096; idx += 256) {
    int r = idx >> 6, c = idx & 63;
    dst[(size_t)(bx + r) * K + by + c] = tile[c][r];
  }
}

// -------- GEMM 1: qkv = X(4096x1024)bf16 @ WT(3072x1024)bf16, RoPE(+q*1/8) epilogue.
// NO-LDS: each wave loads its own A/B fragments (global_load_dwordx4, full 64B lines;
// x2 wave duplication absorbed by L1/L2). No barrier => loads pipeline across MFMAs. --
__global__ __launch_bounds__(256) void gemm_qkv_rope(const u16* __restrict__ X,
                                                     const u16* __restrict__ WT,
                                                     u16* __restrict__ qb,
                                                     u16* __restrict__ kb,
                                                     u16* __restrict__ vb) {
  const int K = C_;
  int tid = threadIdx.x;
  int lane = tid & 63, wave = tid >> 6;
  int quad = lane >> 4, lr = lane & 15;
  int m0 = blockIdx.y * 128, n0 = blockIdx.x * 128;
  int wrow = (wave >> 1) * 64, wcol = (wave & 1) * 64;

  const u16* pa[4];
  const u16* pb[4];
#pragma unroll
  for (int i = 0; i < 4; i++)
    pa[i] = X + (size_t)(m0 + wrow + i * 16 + lr) * K + quad * 8;
#pragma unroll
  for (int j = 0; j < 4; j++)
    pb[j] = WT + (size_t)(n0 + wcol + j * 16 + lr) * K + quad * 8;

  f32x4 zero = {0.f, 0.f, 0.f, 0.f};
  f32x4 acc[4][4];
#pragma unroll
  for (int i = 0; i < 4; i++)
#pragma unroll
    for (int j = 0; j < 4; j++) acc[i][j] = zero;

  // 2-stage register pipeline: loads for k0+32 issued before MFMAs of k0
  bfrag8 af[2][4], bf[2][4];
#pragma unroll
  for (int i = 0; i < 4; i++) af[0][i] = *(const bfrag8*)(pa[i]);
#pragma unroll
  for (int j = 0; j < 4; j++) bf[0][j] = *(const bfrag8*)(pb[j]);

  for (int k0 = 0; k0 < K; k0 += 32) {
    int cur = (k0 >> 5) & 1, nxt = cur ^ 1;
    if (k0 + 32 < K) {
#pragma unroll
      for (int i = 0; i < 4; i++) af[nxt][i] = *(const bfrag8*)(pa[i] + k0 + 32);
#pragma unroll
      for (int j = 0; j < 4; j++) bf[nxt][j] = *(const bfrag8*)(pb[j] + k0 + 32);
    }
#pragma unroll
    for (int i = 0; i < 4; i++)
#pragma unroll
      for (int j = 0; j < 4; j++) acc[i][j] = MFMA_BF16(af[cur][i], bf[cur][j], acc[i][j]);
  }

  // epilogue: wave's 64 cols = one (which, head). q pre-scaled by 1/8.
  int colbase = n0 + wcol;
  int which = colbase >> 10;  // 0=q 1=k 2=v
  int h = (colbase & 1023) >> 6;
  u16* dst = which == 0 ? qb : (which == 1 ? kb : vb);
  float sc0 = (which == 0) ? 0.125f : 1.0f;
  float fr0 = __expf(-0.28782313662425574f * (float)lr);        // ln(10000)/32
  float fr1 = __expf(-0.28782313662425574f * (float)(16 + lr));
#pragma unroll
  for (int i = 0; i < 4; i++) {
#pragma unroll
    for (int r = 0; r < 4; r++) {
      int m = m0 + wrow + i * 16 + quad * 4 + r;
      int b = m >> 11, tt = m & 2047;
      size_t base = ((size_t)(b * H_ + h) * T_ + tt) * D_;
      if (which < 2) {
        float sn, cs;
        __sincosf((float)tt * fr0, &sn, &cs);
        dst[base + lr] = f2bf((acc[i][0][r] * cs - acc[i][2][r] * sn) * sc0);
        dst[base + lr + 32] = f2bf((acc[i][0][r] * sn + acc[i][2][r] * cs) * sc0);
        __sincosf((float)tt * fr1, &sn, &cs);
        dst[base + 16 + lr] = f2bf((acc[i][1][r] * cs - acc[i][3][r] * sn) * sc0);
        dst[base + 48 + lr] = f2bf((acc[i][1][r] * sn + acc[i][3][r] * cs) * sc0);
      } else {
#pragma unroll
        for (int j = 0; j < 4; j++) dst[base + j * 16 + lr] = f2bf(acc[i][j][r]);
      }
    }
  }
}

// -------- transpose V: [b,h,t,d] -> [b,h,d,t] --------
__global__ __launch_bounds__(256) void transpose_v(const u16* __restrict__ v,
                                                   u16* __restrict__ vt) {
  __shared__ u16 tile[64][72];
  int t0 = blockIdx.x * 64;
  int bh = blockIdx.y;
  const u16* src = v + (size_t)bh * T_ * D_;
  u16* dst = vt + (size_t)bh * D_ * T_;
  for (int idx = threadIdx.x; idx < 512; idx += 256) {
    int r = idx >> 3, c8 = (idx & 7) * 8;
    *(uint4*)&tile[r][c8] = *(const uint4*)(src + (size_t)(t0 + r) * D_ + c8);
  }
  __syncthreads();
  for (int idx = threadIdx.x; idx < 512; idx += 256) {
    int d = idx >> 3, t8 = (idx & 7) * 8;
    union { uint4 u; u16 s[8]; } p;
#pragma unroll
    for (int e = 0; e < 8; e++) p.s[e] = tile[t8 + e][d];
    *(uint4*)(dst + (size_t)d * T_ + t0 + t8) = p.u;
  }
}

// -------- attention: causal, S^T form, q-tile 64 (16 rows/wave), kv-tile 32,
// dbuf + single barrier/iter. LDS 21KB => 4 blocks/CU all co-resident (grid 1024,
// quadrant-balanced bq map => exactly 132 iters per CU). XOR-swizzled K/V LDS. --------
__global__ __launch_bounds__(256) void attn_k(const u16* __restrict__ qb,
                                              const u16* __restrict__ kb,
                                              const u16* __restrict__ vtb,
                                              u16* __restrict__ ob) {
  __shared__ __align__(16) u16 Ks[2][32 * 64];   // [t][d-chunk ^ t&7]
  __shared__ __align__(16) u16 Vt[2][64 * 32];   // [d][t-chunk ^ (d>>1)&3]
  __shared__ __align__(16) u16 Pst[4][16 * 40];  // per-wave P [q=16][t=32 +pad]
  int tid = threadIdx.x;
  int lane = tid & 63, wave = tid >> 6;
  int quad = lane >> 4, lr = lane & 15;
  int i = blockIdx.x;
  int x = (i >> 5) & 7, qd = i >> 8;
  int bq = (qd == 0) ? 31 - x : (qd == 1) ? 16 + x : (qd == 2) ? 15 - x : x;
  int bh = i & 31;
  int b = bh >> 4, h = bh & 15;
  const u16* Q = qb + (size_t)bh * T_ * D_;
  const u16* Kp = kb + (size_t)bh * T_ * D_;
  const u16* Vp = vtb + (size_t)bh * D_ * T_;
  int qr0 = bq * 64 + wave * 16;  // this wave's q-row base (global)

  // K staging: 32 rows x 128B; wave covers 8 rows. pos p holds global chunk p^(t&7).
  int r0k = wave * 8;
  int srk = lane >> 3, pk = lane & 7;
  const u16* gk = Kp + (size_t)(r0k + srk) * D_ + ((pk ^ srk) << 3);
  // V^T staging: 64 rows x 64B; wave covers 16 rows. pos p holds chunk p^((d>>1)&3).
  int r0v = wave * 16;
  int srv = lane >> 2, pv = lane & 3;
  const u16* gv = Vp + (size_t)(r0v + srv) * T_ + (((pv ^ ((srv >> 1) & 3))) << 3);

  // read-side swizzled offsets (u16 units), lane constants
  int koff0 = ((quad ^ (lr & 7)) << 3);
  int koff1 = (((4 | quad) ^ (lr & 7)) << 3);
  int voff = ((quad ^ ((lr >> 1) & 3)) << 3);

  // Q fragment as MFMA B-operand: B[n=q][k=d]
  bfrag8 qf[2];
#pragma unroll
  for (int ks = 0; ks < 2; ks++)
    qf[ks] = *(const bfrag8*)(Q + (size_t)(qr0 + lr) * D_ + ks * 32 + quad * 8);

  f32x4 zero = {0.f, 0.f, 0.f, 0.f};
  f32x4 o[4];
#pragma unroll
  for (int nn = 0; nn < 4; nn++) o[nn] = zero;
  float psum = 0.f;

  int niter = 2 * bq + 2;
  load_lds16(gk, &Ks[0][r0k * 64]);
  load_lds16(gv, &Vt[0][r0v * 32]);

  int buf = 0;
  for (int it = 0; it < niter; it++) {
    __syncthreads();  // drains loads for tile `it` (issued one compute-phase ago)
    if (it + 1 < niter) {
      int tkn = (it + 1) * 32;
      load_lds16(gk + (size_t)tkn * D_, &Ks[buf ^ 1][r0k * 64]);
      load_lds16(gv + tkn, &Vt[buf ^ 1][r0v * 32]);
    }
    int tk = it * 32;
    if (tk < qr0 + 16) {  // wave-uniform compute gate
      const u16* ks_ = Ks[buf];
      const u16* vt_ = Vt[buf];

      // S^T = K Q^T : 32 kv-rows x 16 q-cols (A=K swizzled, B=Q)
      f32x4 s[2];
      s[0] = zero; s[1] = zero;
#pragma unroll
      for (int j = 0; j < 2; j++) {
        bfrag8 kf0 = *(const bfrag8*)&ks_[(j * 16 + lr) * 64 + koff0];
        bfrag8 kf1 = *(const bfrag8*)&ks_[(j * 16 + lr) * 64 + koff1];
        s[j] = MFMA_BF16(kf0, qf[0], s[j]);
        s[j] = MFMA_BF16(kf1, qf[1], s[j]);
      }

      bool edge = (tk + 32 > qr0);  // wave-uniform
#pragma unroll
      for (int j = 0; j < 2; j++) {
        float p[4];
#pragma unroll
        for (int r = 0; r < 4; r++) {
          float e = __expf(s[j][r]);
          if (edge) {
            int tg = tk + j * 16 + quad * 4 + r;
            e = (tg <= qr0 + lr) ? e : 0.f;
          }
          p[r] = e;
          psum += e;
        }
        u32 u0 = __builtin_bit_cast(u32, p[0]) + 0x8000u;
        u32 u1 = __builtin_bit_cast(u32, p[1]) + 0x8000u;
        u32 u2 = __builtin_bit_cast(u32, p[2]) + 0x8000u;
        u32 u3 = __builtin_bit_cast(u32, p[3]) + 0x8000u;
        uint2 pk2;
        pk2.x = (u0 >> 16) | (u1 & 0xffff0000u);
        pk2.y = (u2 >> 16) | (u3 & 0xffff0000u);
        *(uint2*)&Pst[wave][lr * 40 + j * 16 + quad * 4] = pk2;
      }

      // O += P V : A = P[q][t] (b128), B = V^T[d][t] swizzled
      bfrag8 pf = *(const bfrag8*)&Pst[wave][lr * 40 + quad * 8];
#pragma unroll
      for (int nn = 0; nn < 4; nn++) {
        bfrag8 vf = *(const bfrag8*)&vt_[(nn * 16 + lr) * 32 + voff];
        o[nn] = MFMA_BF16(pf, vf, o[nn]);
      }
    }
    buf ^= 1;
  }

  // total row-sum: reduce over the 4 quads
  float l = psum;
  l += __shfl_xor(l, 16, 64);
  l += __shfl_xor(l, 32, 64);
  float linv = 1.0f / l;

#pragma unroll
  for (int r = 0; r < 4; r++) {
    float lrec = __shfl(linv, quad * 4 + r, 64);
    int row = qr0 + quad * 4 + r;
#pragma unroll
    for (int nn = 0; nn < 4; nn++)
      ob[(size_t)(b * T_ + row) * C_ + h * 64 + nn * 16 + lr] = f2bf(o[nn][r] * lrec);
  }
}

// -------- GEMM 2: out(f32) = A(4096x1024)bf16 @ WT(1024x1024)bf16 + bias(f32).
// 64x128 tile (grid 512), dbuf LDS, single barrier per iter. --------
__global__ __launch_bounds__(256) void gemm_proj(const u16* __restrict__ A,
                                                 const u16* __restrict__ WT,
                                                 const float* __restrict__ bias,
                                                 float* __restrict__ out) {
  const int K = C_;
  __shared__ __align__(16) u16 As[2][64 * 32];
  __shared__ __align__(16) u16 Bs[2][128 * 32];
  int tid = threadIdx.x;
  int lane = tid & 63, wave = tid >> 6;
  int quad = lane >> 4, lr = lane & 15;
  int m0 = blockIdx.y * 64, n0 = blockIdx.x * 128;
  int wcol = wave * 32;
  int srow = lane >> 2, skc = (lane & 3) * 8;

  f32x4 zero = {0.f, 0.f, 0.f, 0.f};
  f32x4 acc[4][2];
#pragma unroll
  for (int i = 0; i < 4; i++)
#pragma unroll
    for (int j = 0; j < 2; j++) acc[i][j] = zero;

  const u16* ga = A + (size_t)(m0 + wave * 16 + srow) * K + skc;
  const u16* gb0 = WT + (size_t)(n0 + wave * 32 + srow) * K + skc;
  const u16* gb1 = WT + (size_t)(n0 + wave * 32 + 16 + srow) * K + skc;

  load_lds16(ga, &As[0][wave * 16 * 32]);
  load_lds16(gb0, &Bs[0][wave * 32 * 32]);
  load_lds16(gb1, &Bs[0][(wave * 32 + 16) * 32]);

  int buf = 0;
  for (int k0 = 0; k0 < K; k0 += 32) {
    __syncthreads();
    if (k0 + 32 < K) {
      load_lds16(ga + k0 + 32, &As[buf ^ 1][wave * 16 * 32]);
      load_lds16(gb0 + k0 + 32, &Bs[buf ^ 1][wave * 32 * 32]);
      load_lds16(gb1 + k0 + 32, &Bs[buf ^ 1][(wave * 32 + 16) * 32]);
    }
    bfrag8 af[4], bfr[2];
#pragma unroll
    for (int i = 0; i < 4; i++)
      af[i] = *(const bfrag8*)&As[buf][(i * 16 + lr) * 32 + quad * 8];
#pragma unroll
    for (int j = 0; j < 2; j++)
      bfr[j] = *(const bfrag8*)&Bs[buf][(wcol + j * 16 + lr) * 32 + quad * 8];
#pragma unroll
    for (int i = 0; i < 4; i++)
#pragma unroll
      for (int j = 0; j < 2; j++) acc[i][j] = MFMA_BF16(af[i], bfr[j], acc[i][j]);
    buf ^= 1;
  }

#pragma unroll
  for (int i = 0; i < 4; i++)
#pragma unroll
    for (int r = 0; r < 4; r++) {
      int m = m0 + i * 16 + quad * 4 + r;
#pragma unroll
      for (int j = 0; j < 2; j++) {
        int n = n0 + wcol + j * 16 + lr;
        out[(size_t)m * C_ + n] = acc[i][j][r] + bias[n];
      }
    }
}

extern "C" void kernel_launch(void* const* d_in, const int* in_sizes, int n_in,
                              void* d_out, int out_size, void* d_ws, size_t ws_size,
                              hipStream_t stream) {
  const float* x = (const float*)d_in[0];       // [4096,1024] f32
  const float* w_qkv = (const float*)d_in[1];   // [1024,3072] f32
  const float* w_proj = (const float*)d_in[2];  // [1024,1024] f32
  const float* b_proj = (const float*)d_in[3];  // [1024] f32

  char* w = (char*)d_ws;
  u16* xb = (u16*)(w + 256);                 // 4096*1024 bf16
  u16* vtb = xb;                             // alias: used after xb is dead
  u16* regA = xb + (size_t)4096 * 1024;      // max(wqkvT, abuf)
  u16* wqkvT = regA;                         // 3072*1024 (dead after gemm_qkv)
  u16* abuf = regA;                          // 4096*1024 (written by attn)
  u16* wprojT = regA + (size_t)4096 * 1024;  // 1024*1024
  u16* qbuf = wprojT + (size_t)1024 * 1024;
  u16* kbuf = qbuf + (size_t)B_ * H_ * T_ * D_;
  u16* vbuf = kbuf + (size_t)B_ * H_ * T_ * D_;

  prep_k<<<3072, 256, 0, stream>>>(x, w_qkv, w_proj, xb, wqkvT, wprojT);
  gemm_qkv_rope<<<dim3(NQKV_ / 128, (B_ * T_) / 128), 256, 0, stream>>>(xb, wqkvT, qbuf, kbuf, vbuf);
  transpose_v<<<dim3(T_ / 64, B_ * H_), 256, 0, stream>>>(vbuf, vtb);
  attn_k<<<1024, 256, 0, stream>>>(qbuf, kbuf, vtb, abuf);
  gemm_proj<<<dim3(C_ / 128, (B_ * T_) / 64), 256, 0, stream>>>(abuf, wprojT, b_proj, (float*)d_out);
}

// Round 9
// 204.334 us; speedup vs baseline: 1.2762x; 1.2762x over previous
//
#include <hip/hip_runtime.h>
#include <math.h>

typedef unsigned short u16;
typedef unsigned int u32;
typedef __bf16 bfrag8 __attribute__((ext_vector_type(8)));
typedef float f32x4 __attribute__((ext_vector_type(4)));

#define B_ 2
#define T_ 2048
#define H_ 16
#define D_ 64
#define C_ 1024
#define NQKV_ 3072

#define MFMA_BF16(a, b, c) __builtin_amdgcn_mfma_f32_16x16x32_bf16((a), (b), (c), 0, 0, 0)

__device__ __forceinline__ u16 f2bf(float f) {
  u32 u = __builtin_bit_cast(u32, f);
  u += 0x7fffu + ((u >> 16) & 1u);  // RNE
  return (u16)(u >> 16);
}

// async global->LDS, 16B/lane; lds dest = wave-uniform base + lane*16
__device__ __forceinline__ void load_lds16(const u16* gp, u16* lp) {
  __builtin_amdgcn_global_load_lds(
      (const __attribute__((address_space(1))) u32*)(const void*)gp,
      (__attribute__((address_space(3))) u32*)(void*)lp, 16, 0, 0);
}

// -------- fused prep: convert x->bf16 | transpose wqkv | transpose wproj --------
__global__ __launch_bounds__(256) void prep_k(const float* __restrict__ x,
                                              const float* __restrict__ wqkv,
                                              const float* __restrict__ wproj,
                                              u16* __restrict__ xb,
                                              u16* __restrict__ wqkvT,
                                              u16* __restrict__ wprojT) {
  __shared__ u16 tile[64][65];
  int bi = blockIdx.x;
  if (bi < 2048) {  // convert x
    size_t i = ((size_t)bi * 256 + threadIdx.x) * 8;
    const float* s = x + i;
    float4 a = *(const float4*)s, b = *(const float4*)(s + 4);
    union { uint4 v; u16 h[8]; } t;
    t.h[0] = f2bf(a.x); t.h[1] = f2bf(a.y); t.h[2] = f2bf(a.z); t.h[3] = f2bf(a.w);
    t.h[4] = f2bf(b.x); t.h[5] = f2bf(b.y); t.h[6] = f2bf(b.z); t.h[7] = f2bf(b.w);
    *(uint4*)(xb + i) = t.v;
    return;
  }
  const float* src;
  u16* dst;
  int K, N, bx, by;
  if (bi < 2816) {  // wqkv [1024][3072] -> [3072][1024]
    int t = bi - 2048;
    src = wqkv; dst = wqkvT; K = C_; N = NQKV_;
    bx = (t % 48) * 64; by = (t / 48) * 64;
  } else {  // wproj [1024][1024] -> [1024][1024]
    int t = bi - 2816;
    src = wproj; dst = wprojT; K = C_; N = C_;
    bx = (t & 15) * 64; by = (t >> 4) * 64;
  }
  for (int idx = threadIdx.x; idx < 4096; idx += 256) {
    int r = idx >> 6, c = idx & 63;
    tile[r][c] = f2bf(src[(size_t)(by + r) * N + bx + c]);
  }
  __syncthreads();
  for (int idx = threadIdx.x; idx < 4096; idx += 256) {
    int r = idx >> 6, c = idx & 63;
    dst[(size_t)(bx + r) * K + by + c] = tile[c][r];
  }
}

// -------- GEMM 1: qkv = X(4096x1024)bf16 @ WT(3072x1024)bf16, RoPE(+q*1/8) epilogue.
// dbuf LDS, single barrier per K-iter (r7 known-good; r8's no-LDS variant was
// latency-bound at 2.4x worse — register pipelines can't cover L2 latency here). ----
__global__ __launch_bounds__(256) void gemm_qkv_rope(const u16* __restrict__ X,
                                                     const u16* __restrict__ WT,
                                                     u16* __restrict__ qb,
                                                     u16* __restrict__ kb,
                                                     u16* __restrict__ vb) {
  const int K = C_;
  __shared__ __align__(16) u16 As[2][128 * 32];
  __shared__ __align__(16) u16 Bs[2][128 * 32];
  int tid = threadIdx.x;
  int lane = tid & 63, wave = tid >> 6;
  int quad = lane >> 4, lr = lane & 15;
  int m0 = blockIdx.y * 128, n0 = blockIdx.x * 128;
  int wrow = (wave >> 1) * 64, wcol = (wave & 1) * 64;
  int r0 = wave * 32;
  int srow = lane >> 2, skc = (lane & 3) * 8;

  f32x4 zero = {0.f, 0.f, 0.f, 0.f};
  f32x4 acc[4][4];
#pragma unroll
  for (int i = 0; i < 4; i++)
#pragma unroll
    for (int j = 0; j < 4; j++) acc[i][j] = zero;

  const u16* ga0 = X + (size_t)(m0 + r0 + srow) * K + skc;
  const u16* ga1 = X + (size_t)(m0 + r0 + 16 + srow) * K + skc;
  const u16* gb0 = WT + (size_t)(n0 + r0 + srow) * K + skc;
  const u16* gb1 = WT + (size_t)(n0 + r0 + 16 + srow) * K + skc;

  load_lds16(ga0, &As[0][r0 * 32]);
  load_lds16(ga1, &As[0][(r0 + 16) * 32]);
  load_lds16(gb0, &Bs[0][r0 * 32]);
  load_lds16(gb1, &Bs[0][(r0 + 16) * 32]);

  int buf = 0;
  for (int k0 = 0; k0 < K; k0 += 32) {
    __syncthreads();
    if (k0 + 32 < K) {
      load_lds16(ga0 + k0 + 32, &As[buf ^ 1][r0 * 32]);
      load_lds16(ga1 + k0 + 32, &As[buf ^ 1][(r0 + 16) * 32]);
      load_lds16(gb0 + k0 + 32, &Bs[buf ^ 1][r0 * 32]);
      load_lds16(gb1 + k0 + 32, &Bs[buf ^ 1][(r0 + 16) * 32]);
    }
    bfrag8 af[4], bfr[4];
#pragma unroll
    for (int i = 0; i < 4; i++)
      af[i] = *(const bfrag8*)&As[buf][(wrow + i * 16 + lr) * 32 + quad * 8];
#pragma unroll
    for (int j = 0; j < 4; j++)
      bfr[j] = *(const bfrag8*)&Bs[buf][(wcol + j * 16 + lr) * 32 + quad * 8];
#pragma unroll
    for (int i = 0; i < 4; i++)
#pragma unroll
      for (int j = 0; j < 4; j++) acc[i][j] = MFMA_BF16(af[i], bfr[j], acc[i][j]);
    buf ^= 1;
  }

  // epilogue: wave's 64 cols = one (which, head). q pre-scaled by 1/8.
  int colbase = n0 + wcol;
  int which = colbase >> 10;  // 0=q 1=k 2=v
  int h = (colbase & 1023) >> 6;
  u16* dst = which == 0 ? qb : (which == 1 ? kb : vb);
  float sc0 = (which == 0) ? 0.125f : 1.0f;
  float fr0 = __expf(-0.28782313662425574f * (float)lr);        // ln(10000)/32
  float fr1 = __expf(-0.28782313662425574f * (float)(16 + lr));
#pragma unroll
  for (int i = 0; i < 4; i++) {
#pragma unroll
    for (int r = 0; r < 4; r++) {
      int m = m0 + wrow + i * 16 + quad * 4 + r;
      int b = m >> 11, tt = m & 2047;
      size_t base = ((size_t)(b * H_ + h) * T_ + tt) * D_;
      if (which < 2) {
        float sn, cs;
        __sincosf((float)tt * fr0, &sn, &cs);
        dst[base + lr] = f2bf((acc[i][0][r] * cs - acc[i][2][r] * sn) * sc0);
        dst[base + lr + 32] = f2bf((acc[i][0][r] * sn + acc[i][2][r] * cs) * sc0);
        __sincosf((float)tt * fr1, &sn, &cs);
        dst[base + 16 + lr] = f2bf((acc[i][1][r] * cs - acc[i][3][r] * sn) * sc0);
        dst[base + 48 + lr] = f2bf((acc[i][1][r] * sn + acc[i][3][r] * cs) * sc0);
      } else {
#pragma unroll
        for (int j = 0; j < 4; j++) dst[base + j * 16 + lr] = f2bf(acc[i][j][r]);
      }
    }
  }
}

// -------- transpose V: [b,h,t,d] -> [b,h,d,t] --------
__global__ __launch_bounds__(256) void transpose_v(const u16* __restrict__ v,
                                                   u16* __restrict__ vt) {
  __shared__ u16 tile[64][72];
  int t0 = blockIdx.x * 64;
  int bh = blockIdx.y;
  const u16* src = v + (size_t)bh * T_ * D_;
  u16* dst = vt + (size_t)bh * D_ * T_;
  for (int idx = threadIdx.x; idx < 512; idx += 256) {
    int r = idx >> 3, c8 = (idx & 7) * 8;
    *(uint4*)&tile[r][c8] = *(const uint4*)(src + (size_t)(t0 + r) * D_ + c8);
  }
  __syncthreads();
  for (int idx = threadIdx.x; idx < 512; idx += 256) {
    int d = idx >> 3, t8 = (idx & 7) * 8;
    union { uint4 u; u16 s[8]; } p;
#pragma unroll
    for (int e = 0; e < 8; e++) p.s[e] = tile[t8 + e][d];
    *(uint4*)(dst + (size_t)d * T_ + t0 + t8) = p.u;
  }
}

// -------- attention: causal, S^T form, q-tile 64 (16 rows/wave), kv-tile 32,
// dbuf + single barrier/iter. LDS 21KB + 68 VGPR => high occupancy (grid 1024,
// quadrant-balanced bq map => exactly 132 iters per CU). XOR-swizzled K/V LDS. --------
__global__ __launch_bounds__(256) void attn_k(const u16* __restrict__ qb,
                                              const u16* __restrict__ kb,
                                              const u16* __restrict__ vtb,
                                              u16* __restrict__ ob) {
  __shared__ __align__(16) u16 Ks[2][32 * 64];   // [t][d-chunk ^ t&7]
  __shared__ __align__(16) u16 Vt[2][64 * 32];   // [d][t-chunk ^ (d>>1)&3]
  __shared__ __align__(16) u16 Pst[4][16 * 40];  // per-wave P [q=16][t=32 +pad]
  int tid = threadIdx.x;
  int lane = tid & 63, wave = tid >> 6;
  int quad = lane >> 4, lr = lane & 15;
  int i = blockIdx.x;
  int x = (i >> 5) & 7, qd = i >> 8;
  int bq = (qd == 0) ? 31 - x : (qd == 1) ? 16 + x : (qd == 2) ? 15 - x : x;
  int bh = i & 31;
  int b = bh >> 4, h = bh & 15;
  const u16* Q = qb + (size_t)bh * T_ * D_;
  const u16* Kp = kb + (size_t)bh * T_ * D_;
  const u16* Vp = vtb + (size_t)bh * D_ * T_;
  int qr0 = bq * 64 + wave * 16;  // this wave's q-row base (global)

  // K staging: 32 rows x 128B; wave covers 8 rows. pos p holds global chunk p^(t&7).
  int r0k = wave * 8;
  int srk = lane >> 3, pk = lane & 7;
  const u16* gk = Kp + (size_t)(r0k + srk) * D_ + ((pk ^ srk) << 3);
  // V^T staging: 64 rows x 64B; wave covers 16 rows. pos p holds chunk p^((d>>1)&3).
  int r0v = wave * 16;
  int srv = lane >> 2, pv = lane & 3;
  const u16* gv = Vp + (size_t)(r0v + srv) * T_ + (((pv ^ ((srv >> 1) & 3))) << 3);

  // read-side swizzled offsets (u16 units), lane constants
  int koff0 = ((quad ^ (lr & 7)) << 3);
  int koff1 = (((4 | quad) ^ (lr & 7)) << 3);
  int voff = ((quad ^ ((lr >> 1) & 3)) << 3);

  // Q fragment as MFMA B-operand: B[n=q][k=d]
  bfrag8 qf[2];
#pragma unroll
  for (int ks = 0; ks < 2; ks++)
    qf[ks] = *(const bfrag8*)(Q + (size_t)(qr0 + lr) * D_ + ks * 32 + quad * 8);

  f32x4 zero = {0.f, 0.f, 0.f, 0.f};
  f32x4 o[4];
#pragma unroll
  for (int nn = 0; nn < 4; nn++) o[nn] = zero;
  float psum = 0.f;

  int niter = 2 * bq + 2;
  load_lds16(gk, &Ks[0][r0k * 64]);
  load_lds16(gv, &Vt[0][r0v * 32]);

  int buf = 0;
  for (int it = 0; it < niter; it++) {
    __syncthreads();  // drains loads for tile `it` (issued one compute-phase ago)
    if (it + 1 < niter) {
      int tkn = (it + 1) * 32;
      load_lds16(gk + (size_t)tkn * D_, &Ks[buf ^ 1][r0k * 64]);
      load_lds16(gv + tkn, &Vt[buf ^ 1][r0v * 32]);
    }
    int tk = it * 32;
    if (tk < qr0 + 16) {  // wave-uniform compute gate
      const u16* ks_ = Ks[buf];
      const u16* vt_ = Vt[buf];

      // S^T = K Q^T : 32 kv-rows x 16 q-cols (A=K swizzled, B=Q)
      f32x4 s[2];
      s[0] = zero; s[1] = zero;
#pragma unroll
      for (int j = 0; j < 2; j++) {
        bfrag8 kf0 = *(const bfrag8*)&ks_[(j * 16 + lr) * 64 + koff0];
        bfrag8 kf1 = *(const bfrag8*)&ks_[(j * 16 + lr) * 64 + koff1];
        s[j] = MFMA_BF16(kf0, qf[0], s[j]);
        s[j] = MFMA_BF16(kf1, qf[1], s[j]);
      }

      bool edge = (tk + 32 > qr0);  // wave-uniform
#pragma unroll
      for (int j = 0; j < 2; j++) {
        float p[4];
#pragma unroll
        for (int r = 0; r < 4; r++) {
          float e = __expf(s[j][r]);
          if (edge) {
            int tg = tk + j * 16 + quad * 4 + r;
            e = (tg <= qr0 + lr) ? e : 0.f;
          }
          p[r] = e;
          psum += e;
        }
        u32 u0 = __builtin_bit_cast(u32, p[0]) + 0x8000u;
        u32 u1 = __builtin_bit_cast(u32, p[1]) + 0x8000u;
        u32 u2 = __builtin_bit_cast(u32, p[2]) + 0x8000u;
        u32 u3 = __builtin_bit_cast(u32, p[3]) + 0x8000u;
        uint2 pk2;
        pk2.x = (u0 >> 16) | (u1 & 0xffff0000u);
        pk2.y = (u2 >> 16) | (u3 & 0xffff0000u);
        *(uint2*)&Pst[wave][lr * 40 + j * 16 + quad * 4] = pk2;
      }

      // O += P V : A = P[q][t] (b128), B = V^T[d][t] swizzled
      bfrag8 pf = *(const bfrag8*)&Pst[wave][lr * 40 + quad * 8];
#pragma unroll
      for (int nn = 0; nn < 4; nn++) {
        bfrag8 vf = *(const bfrag8*)&vt_[(nn * 16 + lr) * 32 + voff];
        o[nn] = MFMA_BF16(pf, vf, o[nn]);
      }
    }
    buf ^= 1;
  }

  // total row-sum: reduce over the 4 quads
  float l = psum;
  l += __shfl_xor(l, 16, 64);
  l += __shfl_xor(l, 32, 64);
  float linv = 1.0f / l;

#pragma unroll
  for (int r = 0; r < 4; r++) {
    float lrec = __shfl(linv, quad * 4 + r, 64);
    int row = qr0 + quad * 4 + r;
#pragma unroll
    for (int nn = 0; nn < 4; nn++)
      ob[(size_t)(b * T_ + row) * C_ + h * 64 + nn * 16 + lr] = f2bf(o[nn][r] * lrec);
  }
}

// -------- GEMM 2: out(f32) = A(4096x1024)bf16 @ WT(1024x1024)bf16 + bias(f32).
// 64x128 tile (grid 512), dbuf LDS, single barrier per iter. --------
__global__ __launch_bounds__(256) void gemm_proj(const u16* __restrict__ A,
                                                 const u16* __restrict__ WT,
                                                 const float* __restrict__ bias,
                                                 float* __restrict__ out) {
  const int K = C_;
  __shared__ __align__(16) u16 As[2][64 * 32];
  __shared__ __align__(16) u16 Bs[2][128 * 32];
  int tid = threadIdx.x;
  int lane = tid & 63, wave = tid >> 6;
  int quad = lane >> 4, lr = lane & 15;
  int m0 = blockIdx.y * 64, n0 = blockIdx.x * 128;
  int wcol = wave * 32;
  int srow = lane >> 2, skc = (lane & 3) * 8;

  f32x4 zero = {0.f, 0.f, 0.f, 0.f};
  f32x4 acc[4][2];
#pragma unroll
  for (int i = 0; i < 4; i++)
#pragma unroll
    for (int j = 0; j < 2; j++) acc[i][j] = zero;

  const u16* ga = A + (size_t)(m0 + wave * 16 + srow) * K + skc;
  const u16* gb0 = WT + (size_t)(n0 + wave * 32 + srow) * K + skc;
  const u16* gb1 = WT + (size_t)(n0 + wave * 32 + 16 + srow) * K + skc;

  load_lds16(ga, &As[0][wave * 16 * 32]);
  load_lds16(gb0, &Bs[0][wave * 32 * 32]);
  load_lds16(gb1, &Bs[0][(wave * 32 + 16) * 32]);

  int buf = 0;
  for (int k0 = 0; k0 < K; k0 += 32) {
    __syncthreads();
    if (k0 + 32 < K) {
      load_lds16(ga + k0 + 32, &As[buf ^ 1][wave * 16 * 32]);
      load_lds16(gb0 + k0 + 32, &Bs[buf ^ 1][wave * 32 * 32]);
      load_lds16(gb1 + k0 + 32, &Bs[buf ^ 1][(wave * 32 + 16) * 32]);
    }
    bfrag8 af[4], bfr[2];
#pragma unroll
    for (int i = 0; i < 4; i++)
      af[i] = *(const bfrag8*)&As[buf][(i * 16 + lr) * 32 + quad * 8];
#pragma unroll
    for (int j = 0; j < 2; j++)
      bfr[j] = *(const bfrag8*)&Bs[buf][(wcol + j * 16 + lr) * 32 + quad * 8];
#pragma unroll
    for (int i = 0; i < 4; i++)
#pragma unroll
      for (int j = 0; j < 2; j++) acc[i][j] = MFMA_BF16(af[i], bfr[j], acc[i][j]);
    buf ^= 1;
  }

#pragma unroll
  for (int i = 0; i < 4; i++)
#pragma unroll
    for (int r = 0; r < 4; r++) {
      int m = m0 + i * 16 + quad * 4 + r;
#pragma unroll
      for (int j = 0; j < 2; j++) {
        int n = n0 + wcol + j * 16 + lr;
        out[(size_t)m * C_ + n] = acc[i][j][r] + bias[n];
      }
    }
}

extern "C" void kernel_launch(void* const* d_in, const int* in_sizes, int n_in,
                              void* d_out, int out_size, void* d_ws, size_t ws_size,
                              hipStream_t stream) {
  const float* x = (const float*)d_in[0];       // [4096,1024] f32
  const float* w_qkv = (const float*)d_in[1];   // [1024,3072] f32
  const float* w_proj = (const float*)d_in[2];  // [1024,1024] f32
  const float* b_proj = (const float*)d_in[3];  // [1024] f32

  char* w = (char*)d_ws;
  u16* xb = (u16*)(w + 256);                 // 4096*1024 bf16
  u16* vtb = xb;                             // alias: used after xb is dead
  u16* regA = xb + (size_t)4096 * 1024;      // max(wqkvT, abuf)
  u16* wqkvT = regA;                         // 3072*1024 (dead after gemm_qkv)
  u16* abuf = regA;                          // 4096*1024 (written by attn)
  u16* wprojT = regA + (size_t)4096 * 1024;  // 1024*1024
  u16* qbuf = wprojT + (size_t)1024 * 1024;
  u16* kbuf = qbuf + (size_t)B_ * H_ * T_ * D_;
  u16* vbuf = kbuf + (size_t)B_ * H_ * T_ * D_;

  prep_k<<<3072, 256, 0, stream>>>(x, w_qkv, w_proj, xb, wqkvT, wprojT);
  gemm_qkv_rope<<<dim3(NQKV_ / 128, (B_ * T_) / 128), 256, 0, stream>>>(xb, wqkvT, qbuf, kbuf, vbuf);
  transpose_v<<<dim3(T_ / 64, B_ * H_), 256, 0, stream>>>(vbuf, vtb);
  attn_k<<<1024, 256, 0, stream>>>(qbuf, kbuf, vtb, abuf);
  gemm_proj<<<dim3(C_ / 128, (B_ * T_) / 64), 256, 0, stream>>>(abuf, wprojT, b_proj, (float*)d_out);
}